// Round 1
// 112.128 us; speedup vs baseline: 1.0242x; 1.0242x over previous
//
#include <hip/hip_runtime.h>
#include <hip/hip_cooperative_groups.h>

namespace cg = cooperative_groups;

// LaplacianReg: B=32, V=65536, K=8, C=3, fp32 in/out.
// res[b,v,c] = ( d[b,v,c] + sum_k w[v,k]*d[b,idx[v,k],c] )^2,  d = out - tgt
// Strategy: transpose d to bf16 (v, b, c) rows of 192B so one neighbor gather
// serves all 32 batches x 3 channels; compute fp32; coalesced fp32 output.
// This version: single cooperative kernel (phase1 -> grid.sync -> phase2),
// direct broadcast idx/w loads (no LDS staging barrier), dwordx3 gathers.
#define BB 32
#define VV 65536
#define KK 8
#define CC 3

constexpr int TV   = 64;              // v-tile per block
constexpr int ROW  = BB * CC;         // 96 elems per transposed v-row
constexpr int PROW = ROW + 1;         // LDS pad
constexpr int TILE_ELEMS = TV * ROW;  // 6144
constexpr int ROWU = ROW / 2;         // 48 uints per bf16 row (192B)

__device__ __forceinline__ unsigned int f2bf(float f) {
  unsigned int u = __float_as_uint(f);
  u += 0x7FFFu + ((u >> 16) & 1u);    // round-to-nearest-even
  return u >> 16;
}
__device__ __forceinline__ float bflo(unsigned int u) { return __uint_as_float(u << 16); }
__device__ __forceinline__ float bfhi(unsigned int u) { return __uint_as_float(u & 0xFFFF0000u); }

struct U3 { unsigned int x, y, z; };  // 12B, 4B-aligned -> global_load_dwordx3

// ---------------------------------------------------------------------------
// Phase 1: dt[v][b][c] = bf16(out[b,v,c] - tgt[b,v,c]), via LDS tile transpose.
// ---------------------------------------------------------------------------
__device__ __forceinline__ void do_transpose_sub(
    const float* __restrict__ outp, const float* __restrict__ tgtp,
    unsigned int* __restrict__ dt, float* tile, int v0, int t) {
  const float4* o4 = (const float4*)outp;
  const float4* t4 = (const float4*)tgtp;
  const int src_base4 = (v0 * CC) >> 2;           // exact: v0 multiple of 64
  #pragma unroll
  for (int l4 = t; l4 < TILE_ELEMS / 4; l4 += 256) {
    int b  = l4 / (TV * CC / 4);                  // 48 float4 per b
    int j4 = l4 - b * (TV * CC / 4);
    int src = b * (VV * CC / 4) + src_base4 + j4;
    float4 a = o4[src];
    float4 g = t4[src];
    float dv[4] = {a.x - g.x, a.y - g.y, a.z - g.z, a.w - g.w};
    int j = 4 * j4;
    #pragma unroll
    for (int q = 0; q < 4; q++) {
      int jj = j + q;
      int vrel = jj / CC, c = jj - vrel * CC;
      tile[vrel * PROW + b * CC + c] = dv[q];
    }
  }
  __syncthreads();

  // Pack 8 consecutive elems -> uint4 of bf16 pairs. 8 | 96, never crosses rows.
  uint4* dst = (uint4*)(dt + (size_t)v0 * ROWU);  // byte offset v0*192, 16B aligned
  #pragma unroll
  for (int i8 = t; i8 < TILE_ELEMS / 8; i8 += 256) {
    int e = i8 * 8;
    int vrel = e / ROW, r = e - vrel * ROW;
    const float* p = &tile[vrel * PROW + r];
    uint4 o;
    o.x = f2bf(p[0]) | (f2bf(p[1]) << 16);
    o.y = f2bf(p[2]) | (f2bf(p[3]) << 16);
    o.z = f2bf(p[4]) | (f2bf(p[5]) << 16);
    o.w = f2bf(p[6]) | (f2bf(p[7]) << 16);
    dst[i8] = o;
  }
}

// ---------------------------------------------------------------------------
// Phase 2: 16-lane group per v, lane l covers batches 2l,2l+1 (6 bf16 = one
// dwordx3 per gather row). idx/w loaded directly (group-uniform broadcast).
// Output restaged via LDS for coalesced fp32 float4 writes in (B,V,C).
// ---------------------------------------------------------------------------
__device__ __forceinline__ void do_gather(
    const unsigned int* __restrict__ dt, const int* __restrict__ nidx,
    const float* __restrict__ nw, float* __restrict__ res,
    float* rtile, int v0, int t) {
  const int g = t >> 4;   // 16 groups per block
  const int l = t & 15;   // lane within group; covers b = 2l, 2l+1
  #pragma unroll 2
  for (int i = 0; i < TV / 16; i++) {
    const int vrel = i * 16 + g;
    const int v    = v0 + vrel;

    // Group-uniform idx/w: 16 lanes share the address -> broadcast loads.
    const int4*   ip = (const int4*)(nidx + (size_t)v * KK);
    const float4* wp = (const float4*)(nw + (size_t)v * KK);
    int4   ia = ip[0], ib = ip[1];
    float4 wa = wp[0], wb = wp[1];
    int   nbk[KK] = {ia.x, ia.y, ia.z, ia.w, ib.x, ib.y, ib.z, ib.w};
    float wk[KK]  = {wa.x, wa.y, wa.z, wa.w, wb.x, wb.y, wb.z, wb.w};

    // self term (dwordx3)
    U3 s = *(const U3*)(dt + (size_t)v * ROWU + 3 * l);
    float x0 = bflo(s.x), y0 = bfhi(s.x), z0 = bflo(s.y);
    float x1 = bfhi(s.y), y1 = bflo(s.z), z1 = bfhi(s.z);

    #pragma unroll
    for (int k = 0; k < KK; k++) {
      U3 u = *(const U3*)(dt + (size_t)nbk[k] * ROWU + 3 * l);
      const float wt = wk[k];
      x0 = fmaf(wt, bflo(u.x), x0);
      y0 = fmaf(wt, bfhi(u.x), y0);
      z0 = fmaf(wt, bflo(u.y), z0);
      x1 = fmaf(wt, bfhi(u.y), x1);
      y1 = fmaf(wt, bflo(u.z), y1);
      z1 = fmaf(wt, bfhi(u.z), z1);
    }
    float* rp = &rtile[vrel * PROW + 6 * l];  // (b=2l,c0..2),(b=2l+1,c0..2)
    rp[0] = x0 * x0; rp[1] = y0 * y0; rp[2] = z0 * z0;
    rp[3] = x1 * x1; rp[4] = y1 * y1; rp[5] = z1 * z1;
  }
  __syncthreads();

  // Coalesced writeback to (B,V,C).
  float4* r4 = (float4*)res;
  const int dst_base4 = (v0 * CC) >> 2;
  #pragma unroll
  for (int l4 = t; l4 < TILE_ELEMS / 4; l4 += 256) {
    int b  = l4 / (TV * CC / 4);
    int j4 = l4 - b * (TV * CC / 4);
    int j  = 4 * j4;
    float tmp[4];
    #pragma unroll
    for (int q = 0; q < 4; q++) {
      int jj = j + q;
      int vrel = jj / CC, c = jj - vrel * CC;
      tmp[q] = rtile[vrel * PROW + b * CC + c];
    }
    r4[b * (VV * CC / 4) + dst_base4 + j4] = make_float4(tmp[0], tmp[1], tmp[2], tmp[3]);
  }
}

// ---------------------------------------------------------------------------
// Fused cooperative kernel: phase1 -> device-scope fence -> grid sync -> phase2.
// grid = VV/TV = 1024 blocks; __launch_bounds__(256,4) guarantees 4 blocks/CU
// (VGPR<=128, LDS 24.8KB) so all 1024 are co-resident on 256 CUs.
// __threadfence(): dt stores are dirty in the writer XCD's L2; per-XCD L2s are
// NOT cross-coherent, so push them to the LLC before other XCDs gather.
// ---------------------------------------------------------------------------
__global__ __launch_bounds__(256, 4) void lap_fused_coop(
    const float* __restrict__ outp, const float* __restrict__ tgtp,
    const int* __restrict__ nidx, const float* __restrict__ nw,
    unsigned int* __restrict__ dt, float* __restrict__ res) {
  __shared__ float smem[TV * PROW];   // 24.8 KB, reused by both phases
  const int t  = threadIdx.x;
  const int v0 = blockIdx.x * TV;

  do_transpose_sub(outp, tgtp, dt, smem, v0, t);
  __threadfence();
  cg::this_grid().sync();
  do_gather(dt, nidx, nw, res, smem, v0, t);
}

// --------------------------- fallback: two kernels -------------------------
__global__ __launch_bounds__(256) void lap_pass1_transpose_sub(
    const float* __restrict__ outp, const float* __restrict__ tgtp,
    unsigned int* __restrict__ dt) {
  __shared__ float tile[TV * PROW];
  do_transpose_sub(outp, tgtp, dt, tile, blockIdx.x * TV, threadIdx.x);
}

__global__ __launch_bounds__(256) void lap_pass2_gather(
    const unsigned int* __restrict__ dt, const int* __restrict__ nidx,
    const float* __restrict__ nw, float* __restrict__ res) {
  __shared__ float rtile[TV * PROW];
  do_gather(dt, nidx, nw, res, rtile, blockIdx.x * TV, threadIdx.x);
}

// ---------------------------------------------------------------------------
// Fallback (ws too small): fused fp32 direct kernel, one thread per (b,v).
// ---------------------------------------------------------------------------
__global__ __launch_bounds__(256) void lap_fused_fallback(
    const float* __restrict__ outp, const float* __restrict__ tgtp,
    const int* __restrict__ nidx, const float* __restrict__ nw,
    float* __restrict__ res) {
  int tid = blockIdx.x * 256 + threadIdx.x;
  if (tid >= BB * VV) return;
  int v = tid & (VV - 1);
  int b = tid >> 16;
  float ax = 0.f, ay = 0.f, az = 0.f;
  #pragma unroll
  for (int k = 0; k < KK; k++) {
    int   nb = nidx[v * KK + k];
    float wt = nw[v * KK + k];
    const float* po = outp + ((size_t)b * VV + nb) * CC;
    const float* pt = tgtp + ((size_t)b * VV + nb) * CC;
    ax = fmaf(wt, po[0] - pt[0], ax);
    ay = fmaf(wt, po[1] - pt[1], ay);
    az = fmaf(wt, po[2] - pt[2], az);
  }
  const float* so = outp + (size_t)tid * CC;
  const float* st = tgtp + (size_t)tid * CC;
  float dx = so[0] - st[0] + ax;
  float dy = so[1] - st[1] + ay;
  float dz = so[2] - st[2] + az;
  float* rp = res + (size_t)tid * CC;
  rp[0] = dx * dx; rp[1] = dy * dy; rp[2] = dz * dz;
}

extern "C" void kernel_launch(void* const* d_in, const int* in_sizes, int n_in,
                              void* d_out, int out_size, void* d_ws, size_t ws_size,
                              hipStream_t stream) {
  const float* outp = (const float*)d_in[0];
  const float* tgtp = (const float*)d_in[1];
  const int*   nidx = (const int*)d_in[2];
  const float* nw   = (const float*)d_in[3];
  float* res = (float*)d_out;

  const size_t dt_bytes = (size_t)VV * ROW * 2;   // 12.6 MB bf16
  if (ws_size >= dt_bytes) {
    unsigned int* dt = (unsigned int*)d_ws;

    static int coop = -1;   // decided once (at capture); replays reuse the graph
    if (coop < 0) {
      int nb = 0;
      hipError_t e = hipOccupancyMaxActiveBlocksPerMultiprocessor(
          &nb, lap_fused_coop, 256, 0);
      // need nb blocks/CU * 256 CUs >= 1024 blocks co-resident
      coop = (e == hipSuccess && nb >= 4) ? 1 : 0;
    }
    if (coop == 1) {
      void* params[] = {(void*)&outp, (void*)&tgtp, (void*)&nidx,
                        (void*)&nw,   (void*)&dt,   (void*)&res};
      hipError_t e = hipLaunchCooperativeKernel(
          lap_fused_coop, dim3(VV / TV), dim3(256), params, 0u, stream);
      if (e == hipSuccess) return;
      coop = 0;  // fall through to two-kernel path
    }
    lap_pass1_transpose_sub<<<VV / TV, 256, 0, stream>>>(outp, tgtp, dt);
    lap_pass2_gather<<<VV / TV, 256, 0, stream>>>(dt, nidx, nw, res);
  } else {
    lap_fused_fallback<<<(BB * VV) / 256, 256, 0, stream>>>(outp, tgtp, nidx, nw, res);
  }
}